// Round 6
// baseline (477.760 us; speedup 1.0000x reference)
//
#include <hip/hip_runtime.h>

#define F_IN 128
#define F_OUT 64
#define TILE 4096
#define CAP 4608   // per-bucket srcs capacity: mean 4092, sigma 64 -> +8 sigma

// ---- bf16 helpers (manual, RTN) ----
__device__ inline unsigned short f2bf(float f) {
    unsigned int x = __builtin_bit_cast(unsigned int, f);
    unsigned int r = x + 0x7FFFu + ((x >> 16) & 1u);
    return (unsigned short)(r >> 16);
}

// ---------------- S1: atomic-free tile-local bucket sort, single global read ----------------
// Pass 1: read col ONCE -> LDS colbuf + LDS bucket hist + fire-and-forget global deg.
// Scan in LDS. Pass 2: read colbuf (LDS) + row (global, first touch), place edge
// grouped-by-bucket into the tile's own contiguous bpacked region. offT[b][tile]
// holds within-tile exclusive offsets (row-major by bucket for coalesced build2).
__global__ void tile_sort(const int* __restrict__ row, const int* __restrict__ col,
                          int* __restrict__ deg, int* __restrict__ offT,
                          int* __restrict__ bpacked, int E, int NB, int NT) {
    __shared__ int hist[1024];
    __shared__ int gscan[256];
    __shared__ int cur[1024];
    __shared__ int colbuf[TILE];
    const int t = threadIdx.x;            // 256 threads
    const int tile = blockIdx.x;
    const int base = tile * TILE;
    const int n = min(TILE, E - base);

    for (int i = t; i < 1024; i += 256) hist[i] = 0;
    __syncthreads();
    for (int i = t; i < n; i += 256) {
        const int c = col[base + i];
        colbuf[i] = c;
        atomicAdd(&hist[c >> 7], 1);      // LDS bucket hist
        atomicAdd(&deg[c], 1);            // global degree, non-returning
    }
    __syncthreads();

    // scan: each thread owns 4 buckets
    const int h0 = hist[4 * t + 0];
    const int h1 = hist[4 * t + 1];
    const int h2 = hist[4 * t + 2];
    const int h3 = hist[4 * t + 3];
    const int gsum = h0 + h1 + h2 + h3;
    gscan[t] = gsum;
    __syncthreads();
    int incl = gsum;
    for (int off = 1; off < 256; off <<= 1) {
        int v = (t >= off) ? gscan[t - off] : 0;
        __syncthreads();
        incl += v;
        gscan[t] = incl;
        __syncthreads();
    }
    const int gbase = incl - gsum;        // exclusive group base
    cur[4 * t + 0] = gbase;
    cur[4 * t + 1] = gbase + h0;
    cur[4 * t + 2] = gbase + h0 + h1;
    cur[4 * t + 3] = gbase + h0 + h1 + h2;
    __syncthreads();

    // publish per-(bucket, tile) exclusive offsets BEFORE cur is mutated
    for (int b = t; b < NB; b += 256)
        offT[(size_t)b * NT + tile] = cur[b];
    if (t == 0) offT[(size_t)NB * NT + tile] = n;   // sentinel row: tile count
    __syncthreads();

    // placement: LDS-sourced, contiguous within tile region, zero global atomics
    for (int i = t; i < n; i += 256) {
        const int c = colbuf[i];
        const int pos = atomicAdd(&cur[c >> 7], 1);
        bpacked[base + pos] = row[base + i] | ((c & 127) << 17);
    }
}

// ---------------- S2: single-pass run-walk placement into node-sorted srcs ----------------
// One block per 128-node bucket. Cursors/dinv/segs come from the globally
// counted deg (no hist pass -> bpacked read ONCE). Threads walk whole runs
// (avg 5 edges) -- 64 independent chains per wave, no binary search.
__global__ void build2(const int* __restrict__ offT, const int* __restrict__ bpacked,
                       const int* __restrict__ deg, int* __restrict__ srcs,
                       float* __restrict__ dinv, int2* __restrict__ segs,
                       int N, int NT) {
    const int b = blockIdx.x;
    const int t = threadIdx.x;            // 256 threads
    __shared__ int gsc[128];
    __shared__ int cursor[128];
    const int* r0 = offT + (size_t)b * NT;
    const int* r1 = offT + (size_t)(b + 1) * NT;

    // node-degree scan (128 nodes) -> cursors, dinv, segs
    const int node = b * 128 + t;
    int dv_ = 0;
    if (t < 128) { dv_ = (node < N) ? deg[node] : 0; gsc[t] = dv_; }
    __syncthreads();
    for (int off = 1; off < 128; off <<= 1) {
        int v = (t < 128 && t >= off) ? gsc[t - off] : 0;
        __syncthreads();
        if (t < 128) gsc[t] += v;
        __syncthreads();
    }
    const int sbase = b * CAP;
    if (t < 128) {
        const int ex = min(gsc[t] - dv_, CAP);
        cursor[t] = ex;
        if (node < N) {
            dinv[node] = rsqrtf((float)dv_ + 1.0f);   // +1 self-loop
            segs[node] = make_int2(sbase + ex, min(dv_, CAP - ex));
        }
    }
    __syncthreads();

    // single pass: walk runs (one per thread, strided)
    for (int tt = t; tt < NT; tt += 256) {
        const int s = r0[tt], e = r1[tt];
        const int tb = tt * TILE;
        for (int i = s; i < e; i++) {
            const int p = bpacked[tb + i];
            const int pos = atomicAdd(&cursor[p >> 17], 1);
            if (pos < CAP) srcs[sbase + pos] = p & 0x1FFFF;
        }
    }
}

// ---------------- gemm: 64 nodes/block; half-wave owns 8 nodes, lane owns col-quad ----------------
// Each 16B LDS read (wave-broadcast within half) feeds 16 FMAs.
__global__ __launch_bounds__(256) void gemm_kernel(
        const float* __restrict__ x, const float* __restrict__ Wmu,
        const float* __restrict__ Wls, const float* __restrict__ dinv,
        unsigned int* __restrict__ y, int N) {
    __shared__ float xs[64 * F_IN];       // 32 KB
    const int tid = threadIdx.x;          // 0..255
    const int base = blockIdx.x * 64;
    const int nn = min(64, N - base);
    {
        const float4* xg = (const float4*)(x + (size_t)base * F_IN);
        float4* xs4 = (float4*)xs;
        const int cnt = nn * (F_IN / 4);
        for (int i = tid; i < cnt; i += 256) xs4[i] = xg[i];
    }
    __syncthreads();
    const int wv = tid >> 6;              // wave 0..3
    const int lane = tid & 63;
    const int half = lane >> 5;           // 0/1
    const int lp = lane & 31;             // 0..31: col-quad owner
    const int nbase = wv * 16 + half * 8; // this half-wave's 8 nodes
    const float* W0 = (lp < 16) ? Wmu : Wls;
    const int coff = (lp < 16) ? (4 * lp) : (4 * (lp - 16));
    float acc[8][4];
#pragma unroll
    for (int n = 0; n < 8; n++)
#pragma unroll
        for (int c = 0; c < 4; c++) acc[n][c] = 0.f;

    for (int k = 0; k < F_IN; k += 4) {
        const float4 w0 = *(const float4*)&W0[(size_t)(k + 0) * F_OUT + coff];
        const float4 w1 = *(const float4*)&W0[(size_t)(k + 1) * F_OUT + coff];
        const float4 w2 = *(const float4*)&W0[(size_t)(k + 2) * F_OUT + coff];
        const float4 w3 = *(const float4*)&W0[(size_t)(k + 3) * F_OUT + coff];
#pragma unroll
        for (int n = 0; n < 8; n++) {
            const float4 xv = *(const float4*)&xs[(nbase + n) * F_IN + k];
            acc[n][0] = fmaf(xv.x, w0.x, acc[n][0]);
            acc[n][1] = fmaf(xv.x, w0.y, acc[n][1]);
            acc[n][2] = fmaf(xv.x, w0.z, acc[n][2]);
            acc[n][3] = fmaf(xv.x, w0.w, acc[n][3]);
            acc[n][0] = fmaf(xv.y, w1.x, acc[n][0]);
            acc[n][1] = fmaf(xv.y, w1.y, acc[n][1]);
            acc[n][2] = fmaf(xv.y, w1.z, acc[n][2]);
            acc[n][3] = fmaf(xv.y, w1.w, acc[n][3]);
            acc[n][0] = fmaf(xv.z, w2.x, acc[n][0]);
            acc[n][1] = fmaf(xv.z, w2.y, acc[n][1]);
            acc[n][2] = fmaf(xv.z, w2.z, acc[n][2]);
            acc[n][3] = fmaf(xv.z, w2.w, acc[n][3]);
            acc[n][0] = fmaf(xv.w, w3.x, acc[n][0]);
            acc[n][1] = fmaf(xv.w, w3.y, acc[n][1]);
            acc[n][2] = fmaf(xv.w, w3.z, acc[n][2]);
            acc[n][3] = fmaf(xv.w, w3.w, acc[n][3]);
        }
    }
    const int ci = (lp < 16) ? (2 * lp) : (32 + 2 * (lp - 16));
#pragma unroll
    for (int n = 0; n < 8; n++) {
        const int node = base + nbase + n;
        if (node < N) {
            const float dv = dinv[node];
            const unsigned u0 = (unsigned)f2bf(acc[n][0] * dv) |
                                ((unsigned)f2bf(acc[n][1] * dv) << 16);
            const unsigned u1 = (unsigned)f2bf(acc[n][2] * dv) |
                                ((unsigned)f2bf(acc[n][3] * dv) << 16);
            *(uint2*)&y[(size_t)node * 64 + ci] = make_uint2(u0, u1);
        }
    }
}

// ---------------- gather: one WAVE per node; 16 lanes x uint4 per edge, 4 edges/pass ----------------
// Round-2 measured best: 16-deep main loop keeps VGPR at 28 -> 77% occupancy.
__global__ void gather_kernel(const int2* __restrict__ segs, const int* __restrict__ srcs,
                              const uint4* __restrict__ Y, const float* __restrict__ dinv,
                              const float* __restrict__ bmu, const float* __restrict__ bls,
                              float* __restrict__ out, int N) {
    const int wid = threadIdx.x >> 6;
    const int lane = threadIdx.x & 63;
    const int c = blockIdx.x * 4 + wid;
    if (c >= N) return;
    const int2 sg = segs[c];
    const int sb = sg.x;
    const int deg = sg.y;
    const int eg = lane >> 4;        // edge slot within pass (0..3)
    const int q = lane & 15;         // uint4 index within 256B row

    float4 A = make_float4(0.f, 0.f, 0.f, 0.f);   // features 8q+0..3
    float4 B = make_float4(0.f, 0.f, 0.f, 0.f);   // features 8q+4..7

#define ACC(u)                                                        \
    do {                                                              \
        A.x += __builtin_bit_cast(float, (u).x << 16);                \
        A.y += __builtin_bit_cast(float, (u).x & 0xFFFF0000u);        \
        A.z += __builtin_bit_cast(float, (u).y << 16);                \
        A.w += __builtin_bit_cast(float, (u).y & 0xFFFF0000u);        \
        B.x += __builtin_bit_cast(float, (u).z << 16);                \
        B.y += __builtin_bit_cast(float, (u).z & 0xFFFF0000u);        \
        B.z += __builtin_bit_cast(float, (u).w << 16);                \
        B.w += __builtin_bit_cast(float, (u).w & 0xFFFF0000u);        \
    } while (0)

    int i = 0;
    for (; i + 16 <= deg; i += 16) {
        const int e0 = srcs[sb + i + 0 + eg];
        const int e1 = srcs[sb + i + 4 + eg];
        const int e2 = srcs[sb + i + 8 + eg];
        const int e3 = srcs[sb + i + 12 + eg];
        const uint4 u0 = Y[(size_t)e0 * 16 + q];
        const uint4 u1 = Y[(size_t)e1 * 16 + q];
        const uint4 u2 = Y[(size_t)e2 * 16 + q];
        const uint4 u3 = Y[(size_t)e3 * 16 + q];
        ACC(u0); ACC(u1); ACC(u2); ACC(u3);
    }
    for (; i < deg; i += 4) {
        if (i + eg < deg) {
            const int e = srcs[sb + i + eg];
            const uint4 u = Y[(size_t)e * 16 + q];
            ACC(u);
        }
    }

    // combine the 4 edge-slot partials
    A.x += __shfl_xor(A.x, 16); A.y += __shfl_xor(A.y, 16);
    A.z += __shfl_xor(A.z, 16); A.w += __shfl_xor(A.w, 16);
    B.x += __shfl_xor(B.x, 16); B.y += __shfl_xor(B.y, 16);
    B.z += __shfl_xor(B.z, 16); B.w += __shfl_xor(B.w, 16);
    A.x += __shfl_xor(A.x, 32); A.y += __shfl_xor(A.y, 32);
    A.z += __shfl_xor(A.z, 32); A.w += __shfl_xor(A.w, 32);
    B.x += __shfl_xor(B.x, 32); B.y += __shfl_xor(B.y, 32);
    B.z += __shfl_xor(B.z, 32); B.w += __shfl_xor(B.w, 32);

    // self-loop
    {
        const uint4 u = Y[(size_t)c * 16 + q];
        ACC(u);
    }
#undef ACC

    if (lane < 16) {
        const float dv = dinv[c];
        if (q < 8) {
            const float4 b0 = ((const float4*)bmu)[2 * q];
            const float4 b1 = ((const float4*)bmu)[2 * q + 1];
            float* o = out + (size_t)c * F_OUT + q * 8;
            *(float4*)o = make_float4(b0.x + A.x * dv, b0.y + A.y * dv,
                                      b0.z + A.z * dv, b0.w + A.w * dv);
            *(float4*)(o + 4) = make_float4(b1.x + B.x * dv, b1.y + B.y * dv,
                                            b1.z + B.z * dv, b1.w + B.w * dv);
        } else {
            const float4 b0 = ((const float4*)bls)[2 * (q - 8)];
            const float4 b1 = ((const float4*)bls)[2 * (q - 8) + 1];
            float* o = out + (size_t)(N + c) * F_OUT + (q - 8) * 8;
            *(float4*)o = make_float4(b0.x + A.x * dv, b0.y + A.y * dv,
                                      b0.z + A.z * dv, b0.w + A.w * dv);
            *(float4*)(o + 4) = make_float4(b1.x + B.x * dv, b1.y + B.y * dv,
                                            b1.z + B.z * dv, b1.w + B.w * dv);
        }
    }
}

extern "C" void kernel_launch(void* const* d_in, const int* in_sizes, int n_in,
                              void* d_out, int out_size, void* d_ws, size_t ws_size,
                              hipStream_t stream) {
    const float* x   = (const float*)d_in[0];
    const int*   ei  = (const int*)d_in[1];
    const float* Wmu = (const float*)d_in[2];
    const float* bmu = (const float*)d_in[3];
    const float* Wls = (const float*)d_in[4];
    const float* bls = (const float*)d_in[5];
    float* out = (float*)d_out;

    const int N = in_sizes[0] / F_IN;     // 100000
    const int E = in_sizes[1] / 2;        // 3200000
    const int* row = ei;
    const int* col = ei + E;
    const int NB = (N + 127) >> 7;        // 782 buckets of 128 nodes
    const int NT = (E + TILE - 1) / TILE; // 782 tiles of 4096 edges

    // workspace layout (512B aligned):
    char* p = (char*)d_ws;
    auto alloc = [&](size_t bytes) {
        char* r = p;
        p += (bytes + 511) & ~(size_t)511;
        return r;
    };
    int*   deg     = (int*)  alloc((size_t)N * 4);
    int*   offT    = (int*)  alloc((size_t)(NB + 1) * NT * 4);  // [bucket][tile]
    int*   bpacked = (int*)  alloc((size_t)NT * TILE * 4);
    int*   srcs    = (int*)  alloc((size_t)NB * CAP * 4);
    int2*  segs    = (int2*) alloc((size_t)N * 8);
    float* dinv    = (float*)alloc((size_t)N * 4);
    unsigned int* y = (unsigned int*)alloc((size_t)N * F_IN * 2);

    hipMemsetAsync(deg, 0, (size_t)N * 4, stream);
    tile_sort<<<NT, 256, 0, stream>>>(row, col, deg, offT, bpacked, E, NB, NT);
    build2<<<NB, 256, 0, stream>>>(offT, bpacked, deg, srcs, dinv, segs, N, NT);
    gemm_kernel<<<(N + 63) / 64, 256, 0, stream>>>(x, Wmu, Wls, dinv, y, N);
    gather_kernel<<<(N + 3) / 4, 256, 0, stream>>>(segs, srcs, (const uint4*)y,
                                                   dinv, bmu, bls, out, N);
}

// Round 8
// 379.247 us; speedup vs baseline: 1.2598x; 1.2598x over previous
//
#include <hip/hip_runtime.h>

#define F_IN 128
#define F_OUT 64
#define TILE 4096
#define CAP 4608   // per-bucket edge capacity: mean 4092, sigma 64 -> +8 sigma

// ---- bf16 helpers (manual, RTN) ----
__device__ inline unsigned short f2bf(float f) {
    unsigned int x = __builtin_bit_cast(unsigned int, f);
    unsigned int r = x + 0x7FFFu + ((x >> 16) & 1u);
    return (unsigned short)(r >> 16);
}

// ---------------- S1: tile-local bucket sort, 1024 threads, zero global atomics ----------------
// Read col once into LDS; LDS bucket hist; 1024-wide scan; publish offT[b][tile];
// place packed edges grouped by bucket in the tile's own contiguous region.
__global__ __launch_bounds__(1024) void tile_sort(
        const int* __restrict__ row, const int* __restrict__ col,
        int* __restrict__ offT, int* __restrict__ bpacked, int E, int NB, int NT) {
    __shared__ int hist[1024];
    __shared__ int scn[1024];
    __shared__ int colbuf[TILE];
    const int t = threadIdx.x;            // 0..1023
    const int tile = blockIdx.x;
    const int base = tile * TILE;
    const int n = min(TILE, E - base);

    hist[t] = 0;
    __syncthreads();
    for (int i = t; i < n; i += 1024) {
        const int c = col[base + i];
        colbuf[i] = c;
        atomicAdd(&hist[c >> 7], 1);
    }
    __syncthreads();
    // 1024-wide Hillis-Steele inclusive scan (thread owns one bucket)
    const int v = hist[t];
    int incl = v;
    scn[t] = v;
    __syncthreads();
    for (int off = 1; off < 1024; off <<= 1) {
        const int u = (t >= off) ? scn[t - off] : 0;
        __syncthreads();
        incl += u;
        scn[t] = incl;
        __syncthreads();
    }
    const int ex = incl - v;              // exclusive within tile
    if (t < NB) offT[(size_t)t * NT + tile] = ex;
    if (t == 0) offT[(size_t)NB * NT + tile] = n;   // sentinel row
    hist[t] = ex;                         // hist becomes the placement cursor
    __syncthreads();
    for (int i = t; i < n; i += 1024) {
        const int c = colbuf[i];
        const int pos = atomicAdd(&hist[c >> 7], 1);
        bpacked[base + pos] = row[base + i] | ((c & 127) << 17);
    }
}

// ---------------- S2: per-bucket degree hist -> dinv (no global atomics) ----------------
// One block per bucket; thread t walks run t (NT=782 <= 1024 independent chains).
__global__ __launch_bounds__(1024) void deg_hist(
        const int* __restrict__ offT, const int* __restrict__ bpacked,
        float* __restrict__ dinv, int N, int NT) {
    __shared__ int h[128];
    const int b = blockIdx.x;
    const int t = threadIdx.x;
    if (t < 128) h[t] = 0;
    __syncthreads();
    if (t < NT) {
        const int s = offT[(size_t)b * NT + t];
        const int e = offT[(size_t)(b + 1) * NT + t];
        const int* bp = bpacked + (size_t)t * TILE;
        for (int i = s; i < e; i++)
            atomicAdd(&h[bp[i] >> 17], 1);
    }
    __syncthreads();
    const int node = b * 128 + t;
    if (t < 128 && node < N)
        dinv[node] = rsqrtf((float)h[t] + 1.0f);   // +1 self-loop
}

// ---------------- gemm: 64 nodes/block; half-wave owns 8 nodes, lane owns col-quad ----------------
__global__ __launch_bounds__(256) void gemm_kernel(
        const float* __restrict__ x, const float* __restrict__ Wmu,
        const float* __restrict__ Wls, const float* __restrict__ dinv,
        unsigned int* __restrict__ y, int N) {
    __shared__ float xs[64 * F_IN];       // 32 KB
    const int tid = threadIdx.x;          // 0..255
    const int base = blockIdx.x * 64;
    const int nn = min(64, N - base);
    {
        const float4* xg = (const float4*)(x + (size_t)base * F_IN);
        float4* xs4 = (float4*)xs;
        const int cnt = nn * (F_IN / 4);
        for (int i = tid; i < cnt; i += 256) xs4[i] = xg[i];
    }
    __syncthreads();
    const int wv = tid >> 6;              // wave 0..3
    const int lane = tid & 63;
    const int half = lane >> 5;           // 0/1
    const int lp = lane & 31;             // 0..31: col-quad owner
    const int nbase = wv * 16 + half * 8; // this half-wave's 8 nodes
    const float* W0 = (lp < 16) ? Wmu : Wls;
    const int coff = (lp < 16) ? (4 * lp) : (4 * (lp - 16));
    float acc[8][4];
#pragma unroll
    for (int n = 0; n < 8; n++)
#pragma unroll
        for (int c = 0; c < 4; c++) acc[n][c] = 0.f;

    for (int k = 0; k < F_IN; k += 4) {
        const float4 w0 = *(const float4*)&W0[(size_t)(k + 0) * F_OUT + coff];
        const float4 w1 = *(const float4*)&W0[(size_t)(k + 1) * F_OUT + coff];
        const float4 w2 = *(const float4*)&W0[(size_t)(k + 2) * F_OUT + coff];
        const float4 w3 = *(const float4*)&W0[(size_t)(k + 3) * F_OUT + coff];
#pragma unroll
        for (int n = 0; n < 8; n++) {
            const float4 xv = *(const float4*)&xs[(nbase + n) * F_IN + k];
            acc[n][0] = fmaf(xv.x, w0.x, acc[n][0]);
            acc[n][1] = fmaf(xv.x, w0.y, acc[n][1]);
            acc[n][2] = fmaf(xv.x, w0.z, acc[n][2]);
            acc[n][3] = fmaf(xv.x, w0.w, acc[n][3]);
            acc[n][0] = fmaf(xv.y, w1.x, acc[n][0]);
            acc[n][1] = fmaf(xv.y, w1.y, acc[n][1]);
            acc[n][2] = fmaf(xv.y, w1.z, acc[n][2]);
            acc[n][3] = fmaf(xv.y, w1.w, acc[n][3]);
            acc[n][0] = fmaf(xv.z, w2.x, acc[n][0]);
            acc[n][1] = fmaf(xv.z, w2.y, acc[n][1]);
            acc[n][2] = fmaf(xv.z, w2.z, acc[n][2]);
            acc[n][3] = fmaf(xv.z, w2.w, acc[n][3]);
            acc[n][0] = fmaf(xv.w, w3.x, acc[n][0]);
            acc[n][1] = fmaf(xv.w, w3.y, acc[n][1]);
            acc[n][2] = fmaf(xv.w, w3.z, acc[n][2]);
            acc[n][3] = fmaf(xv.w, w3.w, acc[n][3]);
        }
    }
    const int ci = (lp < 16) ? (2 * lp) : (32 + 2 * (lp - 16));
#pragma unroll
    for (int n = 0; n < 8; n++) {
        const int node = base + nbase + n;
        if (node < N) {
            const float dv = dinv[node];
            const unsigned u0 = (unsigned)f2bf(acc[n][0] * dv) |
                                ((unsigned)f2bf(acc[n][1] * dv) << 16);
            const unsigned u1 = (unsigned)f2bf(acc[n][2] * dv) |
                                ((unsigned)f2bf(acc[n][3] * dv) << 16);
            *(uint2*)&y[(size_t)node * 64 + ci] = make_uint2(u0, u1);
        }
    }
}

// ---------------- bucket_gather: in-LDS node sort (two-buffer) + register accumulation ----------------
// One block (1024 thr) per 128-node bucket. No srcs array, no global cursors.
__global__ __launch_bounds__(1024) void bucket_gather(
        const int* __restrict__ offT, const int* __restrict__ bpacked,
        const uint2* __restrict__ Y2, const float* __restrict__ dinv,
        const float* __restrict__ bmu, const float* __restrict__ bls,
        float* __restrict__ out, int N, int NT) {
    __shared__ int eraw[CAP];             // 18 KB: tile-order edges
    __shared__ int elist[CAP];            // 18 KB: node-sorted src ids
    __shared__ int rscan[1024];
    __shared__ int histN[128];
    __shared__ int nodebase[128];
    __shared__ int cursor[128];
    __shared__ int scn2[128];
    __shared__ float dinv_s[128];
    __shared__ int tot_s;
    const int b = blockIdx.x;
    const int t = threadIdx.x;

    // phase 0: run lengths + 1024-wide scan -> flat base per run
    int s = 0, len = 0;
    if (t < NT) {
        s = offT[(size_t)b * NT + t];
        len = offT[(size_t)(b + 1) * NT + t] - s;
    }
    int incl = len;
    rscan[t] = len;
    if (t < 128) histN[t] = 0;
    __syncthreads();
    for (int off = 1; off < 1024; off <<= 1) {
        const int u = (t >= off) ? rscan[t - off] : 0;
        __syncthreads();
        incl += u;
        rscan[t] = incl;
        __syncthreads();
    }
    if (t == 1023) tot_s = incl;
    const int fb = incl - len;
    __syncthreads();
    const int totc = min(tot_s, CAP);

    // phase 1: thread-per-run global read -> eraw (tile order) + node hist
    if (t < NT && len > 0) {
        const int* bp = bpacked + (size_t)t * TILE + s;
        for (int j = 0; j < len; j++) {
            const int pos = fb + j;
            if (pos < CAP) {
                const int p = bp[j];
                eraw[pos] = p;
                atomicAdd(&histN[p >> 17], 1);
            }
        }
    }
    if (t < 128) {
        const int node = b * 128 + t;
        dinv_s[t] = (node < N) ? dinv[node] : 0.f;
    }
    __syncthreads();

    // phase 2: 128-wide scan of node counts -> nodebase/cursor
    int hv = 0, inc2 = 0;
    if (t < 128) { hv = histN[t]; inc2 = hv; scn2[t] = hv; }
    __syncthreads();
    for (int off = 1; off < 128; off <<= 1) {
        const int u = (t < 128 && t >= off) ? scn2[t - off] : 0;
        __syncthreads();
        if (t < 128) { inc2 += u; scn2[t] = inc2; }
        __syncthreads();
    }
    if (t < 128) { nodebase[t] = inc2 - hv; cursor[t] = inc2 - hv; }
    __syncthreads();

    // phase 3: scatter eraw -> elist grouped by node (separate buffers, no aliasing)
    for (int idx = t; idx < totc; idx += 1024) {
        const int p = eraw[idx];
        const int pos = atomicAdd(&cursor[p >> 17], 1);
        elist[pos] = p & 0x1FFFF;
    }
    __syncthreads();

    // phase 4: wave owns 8 nodes; register accumulation; 2 edges per wave-step
    const int w = t >> 6;                 // wave 0..15
    const int l = t & 63;
    const int half = l >> 5;              // edge parity
    const int q = l & 31;                 // uint2 index (feats 4q..4q+3)
    const float4 bias = (q < 16) ? ((const float4*)bmu)[q]
                                 : ((const float4*)bls)[q - 16];
#define UP2(u, A0, A1)                                           \
    A0 += __builtin_bit_cast(float, (u) << 16);                  \
    A1 += __builtin_bit_cast(float, (u) & 0xFFFF0000u);

    for (int nid = w * 8; nid < w * 8 + 8; nid++) {
        const int node = b * 128 + nid;
        if (node >= N) continue;          // wave-uniform
        const int cnt = histN[nid];
        const int nb_ = nodebase[nid];
        float a0 = 0.f, a1 = 0.f, a2 = 0.f, a3 = 0.f;
        int e = half;
        for (; e + 6 < cnt; e += 8) {     // 4 edges in flight per half
            const int s0 = elist[nb_ + e];
            const int s1 = elist[nb_ + e + 2];
            const int s2 = elist[nb_ + e + 4];
            const int s3 = elist[nb_ + e + 6];
            const uint2 u0 = Y2[(size_t)s0 * 32 + q];
            const uint2 u1 = Y2[(size_t)s1 * 32 + q];
            const uint2 u2 = Y2[(size_t)s2 * 32 + q];
            const uint2 u3 = Y2[(size_t)s3 * 32 + q];
            UP2(u0.x, a0, a1) UP2(u0.y, a2, a3)
            UP2(u1.x, a0, a1) UP2(u1.y, a2, a3)
            UP2(u2.x, a0, a1) UP2(u2.y, a2, a3)
            UP2(u3.x, a0, a1) UP2(u3.y, a2, a3)
        }
        for (; e < cnt; e += 2) {
            const int s0 = elist[nb_ + e];
            const uint2 u0 = Y2[(size_t)s0 * 32 + q];
            UP2(u0.x, a0, a1) UP2(u0.y, a2, a3)
        }
        // combine edge-parity halves
        a0 += __shfl_xor(a0, 32);
        a1 += __shfl_xor(a1, 32);
        a2 += __shfl_xor(a2, 32);
        a3 += __shfl_xor(a3, 32);
        // self-loop (post-combine, added once)
        const uint2 us = Y2[(size_t)node * 32 + q];
        UP2(us.x, a0, a1) UP2(us.y, a2, a3)
        const float dv = dinv_s[nid];
        if (half == 0) {
            const float4 r = make_float4(bias.x + a0 * dv, bias.y + a1 * dv,
                                         bias.z + a2 * dv, bias.w + a3 * dv);
            if (q < 16)
                *(float4*)&out[(size_t)node * F_OUT + 4 * q] = r;
            else
                *(float4*)&out[((size_t)N + node) * F_OUT + 4 * (q - 16)] = r;
        }
    }
#undef UP2
}

extern "C" void kernel_launch(void* const* d_in, const int* in_sizes, int n_in,
                              void* d_out, int out_size, void* d_ws, size_t ws_size,
                              hipStream_t stream) {
    const float* x   = (const float*)d_in[0];
    const int*   ei  = (const int*)d_in[1];
    const float* Wmu = (const float*)d_in[2];
    const float* bmu = (const float*)d_in[3];
    const float* Wls = (const float*)d_in[4];
    const float* bls = (const float*)d_in[5];
    float* out = (float*)d_out;

    const int N = in_sizes[0] / F_IN;     // 100000
    const int E = in_sizes[1] / 2;        // 3200000
    const int* row = ei;
    const int* col = ei + E;
    const int NB = (N + 127) >> 7;        // 782 buckets of 128 nodes
    const int NT = (E + TILE - 1) / TILE; // 782 tiles of 4096 edges (<= 1024)

    // workspace layout (512B aligned):
    char* p = (char*)d_ws;
    auto alloc = [&](size_t bytes) {
        char* r = p;
        p += (bytes + 511) & ~(size_t)511;
        return r;
    };
    int*   offT    = (int*)  alloc((size_t)(NB + 1) * NT * 4);  // [bucket][tile]
    int*   bpacked = (int*)  alloc((size_t)NT * TILE * 4);
    float* dinv    = (float*)alloc((size_t)N * 4);
    unsigned int* y = (unsigned int*)alloc((size_t)N * F_IN * 2);

    tile_sort<<<NT, 1024, 0, stream>>>(row, col, offT, bpacked, E, NB, NT);
    deg_hist<<<NB, 1024, 0, stream>>>(offT, bpacked, dinv, N, NT);
    gemm_kernel<<<(N + 63) / 64, 256, 0, stream>>>(x, Wmu, Wls, dinv, y, N);
    bucket_gather<<<NB, 1024, 0, stream>>>(offT, bpacked, (const uint2*)y,
                                           dinv, bmu, bls, out, N, NT);
}

// Round 9
// 370.212 us; speedup vs baseline: 1.2905x; 1.0244x over previous
//
#include <hip/hip_runtime.h>

#define F_IN 128
#define F_OUT 64
#define TILE 4096
#define CAP 4608   // per-bucket edge capacity: mean 4092, sigma 64 -> +8 sigma

// ---- bf16 helpers (manual, RTN) ----
__device__ inline unsigned short f2bf(float f) {
    unsigned int x = __builtin_bit_cast(unsigned int, f);
    unsigned int r = x + 0x7FFFu + ((x >> 16) & 1u);
    return (unsigned short)(r >> 16);
}

// ---------------- K1: per-tile bucket histogram -> cnt[b][t] ----------------
__global__ __launch_bounds__(256) void hist_kernel(
        const int* __restrict__ col, int* __restrict__ cnt, int E, int NB, int NT) {
    __shared__ int h[1024];
    const int t = threadIdx.x;
    const int tile = blockIdx.x;
    const int base = tile * TILE;
    const int n = min(TILE, E - base);
    for (int i = t; i < 1024; i += 256) h[i] = 0;
    __syncthreads();
    for (int i = t; i < n; i += 256)
        atomicAdd(&h[col[base + i] >> 7], 1);
    __syncthreads();
    for (int b = t; b < NB; b += 256)
        cnt[(size_t)b * NT + tile] = h[b];
}

// ---------------- K2: per-bucket scan over tiles -> gbase[b][t] = b*CAP + prefix ----------------
// shfl-hierarchical scan: 1 barrier total. NT <= 1024.
__global__ __launch_bounds__(1024) void scan_kernel(
        const int* __restrict__ cnt, int* __restrict__ gbase,
        int* __restrict__ totB, int NB, int NT) {
    __shared__ int wsum[16];
    const int b = blockIdx.x;
    const int t = threadIdx.x;
    const int lane = t & 63;
    const int w = t >> 6;
    const int v = (t < NT) ? cnt[(size_t)b * NT + t] : 0;
    int x = v;
#pragma unroll
    for (int off = 1; off < 64; off <<= 1) {
        const int y = __shfl_up(x, off, 64);
        if (lane >= off) x += y;
    }
    if (lane == 63) wsum[w] = x;
    __syncthreads();
    int add = 0;
    for (int i = 0; i < w; i++) add += wsum[i];
    x += add;                               // inclusive scan of v
    if (t < NT) gbase[(size_t)b * NT + t] = b * CAP + (x - v);   // exclusive
    if (t == 1023) totB[b] = x;             // bucket total
}

// ---------------- K3: single-pass repack -> global bucket-major bpk ----------------
// Per tile: load this tile's private cursors (disjoint ranges by construction),
// stream edges once, place into bucket segments. Zero global atomics.
__global__ __launch_bounds__(256) void repack_kernel(
        const int* __restrict__ row, const int* __restrict__ col,
        const int* __restrict__ gbase, int* __restrict__ bpk,
        int E, int NB, int NT, int CAPTOT) {
    __shared__ int cur[1024];
    const int t = threadIdx.x;
    const int tile = blockIdx.x;
    const int base = tile * TILE;
    const int n = min(TILE, E - base);
    for (int b = t; b < NB; b += 256)
        cur[b] = gbase[(size_t)b * NT + tile];
    __syncthreads();
    for (int i = t; i < n; i += 256) {
        const int c = col[base + i];
        const int pos = atomicAdd(&cur[c >> 7], 1);
        if (pos < CAPTOT)
            bpk[pos] = row[base + i] | ((c & 127) << 17);
    }
}

// ---------------- K4: per-bucket degree -> deg, dinv (coalesced segment read) ----------------
__global__ __launch_bounds__(256) void deg_kernel(
        const int* __restrict__ bpk, const int* __restrict__ totB,
        int* __restrict__ deg, float* __restrict__ dinv, int N) {
    __shared__ int h[128];
    const int b = blockIdx.x;
    const int t = threadIdx.x;
    if (t < 128) h[t] = 0;
    __syncthreads();
    const int tot = min(totB[b], CAP);
    const int s0 = b * CAP;
    for (int i = t; i < tot; i += 256)
        atomicAdd(&h[bpk[s0 + i] >> 17], 1);
    __syncthreads();
    const int node = b * 128 + t;
    if (t < 128 && node < N) {
        deg[node] = h[t];
        dinv[node] = rsqrtf((float)h[t] + 1.0f);   // +1 self-loop
    }
}

// ---------------- gemm: 64 nodes/block; half-wave owns 8 nodes, lane owns col-quad ----------------
__global__ __launch_bounds__(256) void gemm_kernel(
        const float* __restrict__ x, const float* __restrict__ Wmu,
        const float* __restrict__ Wls, const float* __restrict__ dinv,
        unsigned int* __restrict__ y, int N) {
    __shared__ float xs[64 * F_IN];       // 32 KB
    const int tid = threadIdx.x;          // 0..255
    const int base = blockIdx.x * 64;
    const int nn = min(64, N - base);
    {
        const float4* xg = (const float4*)(x + (size_t)base * F_IN);
        float4* xs4 = (float4*)xs;
        const int cnt = nn * (F_IN / 4);
        for (int i = tid; i < cnt; i += 256) xs4[i] = xg[i];
    }
    __syncthreads();
    const int wv = tid >> 6;              // wave 0..3
    const int lane = tid & 63;
    const int half = lane >> 5;           // 0/1
    const int lp = lane & 31;             // 0..31: col-quad owner
    const int nbase = wv * 16 + half * 8; // this half-wave's 8 nodes
    const float* W0 = (lp < 16) ? Wmu : Wls;
    const int coff = (lp < 16) ? (4 * lp) : (4 * (lp - 16));
    float acc[8][4];
#pragma unroll
    for (int n = 0; n < 8; n++)
#pragma unroll
        for (int c = 0; c < 4; c++) acc[n][c] = 0.f;

    for (int k = 0; k < F_IN; k += 4) {
        const float4 w0 = *(const float4*)&W0[(size_t)(k + 0) * F_OUT + coff];
        const float4 w1 = *(const float4*)&W0[(size_t)(k + 1) * F_OUT + coff];
        const float4 w2 = *(const float4*)&W0[(size_t)(k + 2) * F_OUT + coff];
        const float4 w3 = *(const float4*)&W0[(size_t)(k + 3) * F_OUT + coff];
#pragma unroll
        for (int n = 0; n < 8; n++) {
            const float4 xv = *(const float4*)&xs[(nbase + n) * F_IN + k];
            acc[n][0] = fmaf(xv.x, w0.x, acc[n][0]);
            acc[n][1] = fmaf(xv.x, w0.y, acc[n][1]);
            acc[n][2] = fmaf(xv.x, w0.z, acc[n][2]);
            acc[n][3] = fmaf(xv.x, w0.w, acc[n][3]);
            acc[n][0] = fmaf(xv.y, w1.x, acc[n][0]);
            acc[n][1] = fmaf(xv.y, w1.y, acc[n][1]);
            acc[n][2] = fmaf(xv.y, w1.z, acc[n][2]);
            acc[n][3] = fmaf(xv.y, w1.w, acc[n][3]);
            acc[n][0] = fmaf(xv.z, w2.x, acc[n][0]);
            acc[n][1] = fmaf(xv.z, w2.y, acc[n][1]);
            acc[n][2] = fmaf(xv.z, w2.z, acc[n][2]);
            acc[n][3] = fmaf(xv.z, w2.w, acc[n][3]);
            acc[n][0] = fmaf(xv.w, w3.x, acc[n][0]);
            acc[n][1] = fmaf(xv.w, w3.y, acc[n][1]);
            acc[n][2] = fmaf(xv.w, w3.z, acc[n][2]);
            acc[n][3] = fmaf(xv.w, w3.w, acc[n][3]);
        }
    }
    const int ci = (lp < 16) ? (2 * lp) : (32 + 2 * (lp - 16));
#pragma unroll
    for (int n = 0; n < 8; n++) {
        const int node = base + nbase + n;
        if (node < N) {
            const float dv = dinv[node];
            const unsigned u0 = (unsigned)f2bf(acc[n][0] * dv) |
                                ((unsigned)f2bf(acc[n][1] * dv) << 16);
            const unsigned u1 = (unsigned)f2bf(acc[n][2] * dv) |
                                ((unsigned)f2bf(acc[n][3] * dv) << 16);
            *(uint2*)&y[(size_t)node * 64 + ci] = make_uint2(u0, u1);
        }
    }
}

// ---------------- bucket_gather: coalesced segment -> in-LDS node scatter -> reg accumulation ----------------
__global__ __launch_bounds__(1024) void bucket_gather(
        const int* __restrict__ bpk, const int* __restrict__ deg,
        const uint2* __restrict__ Y2,
        const float* __restrict__ bmu, const float* __restrict__ bls,
        float* __restrict__ out, int N) {
    __shared__ int elist[CAP];            // 18 KB: node-sorted src ids
    __shared__ int hN[128];
    __shared__ int nodebase[128];
    __shared__ int cursor[128];
    __shared__ float dinv_s[128];
    __shared__ int w0sum;
    const int b = blockIdx.x;
    const int t = threadIdx.x;
    const int lane = t & 63;

    // phase 0: deg row (coalesced) + 128-wide shfl scan -> bases/cursors
    int hv = 0;
    if (t < 128) {
        const int node = b * 128 + t;
        hv = (node < N) ? deg[node] : 0;
        dinv_s[t] = rsqrtf((float)hv + 1.0f);
        hN[t] = hv;
    }
    int x = hv;
#pragma unroll
    for (int off = 1; off < 64; off <<= 1) {
        const int y = __shfl_up(x, off, 64);
        if (lane >= off) x += y;
    }
    if (t == 63) w0sum = x;
    __syncthreads();
    if (t >= 64 && t < 128) x += w0sum;
    if (t < 128) { nodebase[t] = x - hv; cursor[t] = x - hv; }
    __syncthreads();
    const int tot = min(nodebase[127] + hN[127], CAP);

    // phase 1: coalesced segment read -> scatter grouped by node
    const int s0 = b * CAP;
    for (int i = t; i < tot; i += 1024) {
        const int p = bpk[s0 + i];
        const int pos = atomicAdd(&cursor[p >> 17], 1);
        if (pos < CAP) elist[pos] = p & 0x1FFFF;
    }
    __syncthreads();

    // phase 2: wave owns 8 nodes; register accumulation; 2 edges per wave-step
    const int w = t >> 6;                 // wave 0..15
    const int half = lane >> 5;           // edge parity
    const int q = lane & 31;              // uint2 index (feats 4q..4q+3)
    const float4 bias = (q < 16) ? ((const float4*)bmu)[q]
                                 : ((const float4*)bls)[q - 16];
#define UP2(u, A0, A1)                                           \
    A0 += __builtin_bit_cast(float, (u) << 16);                  \
    A1 += __builtin_bit_cast(float, (u) & 0xFFFF0000u);

    for (int nid = w * 8; nid < w * 8 + 8; nid++) {
        const int node = b * 128 + nid;
        if (node >= N) continue;          // wave-uniform
        const int cnt = hN[nid];
        const int nb_ = nodebase[nid];
        float a0 = 0.f, a1 = 0.f, a2 = 0.f, a3 = 0.f;
        int e = half;
        for (; e + 6 < cnt; e += 8) {     // 4 edges in flight per half
            const int s_0 = elist[nb_ + e];
            const int s_1 = elist[nb_ + e + 2];
            const int s_2 = elist[nb_ + e + 4];
            const int s_3 = elist[nb_ + e + 6];
            const uint2 u0 = Y2[(size_t)s_0 * 32 + q];
            const uint2 u1 = Y2[(size_t)s_1 * 32 + q];
            const uint2 u2 = Y2[(size_t)s_2 * 32 + q];
            const uint2 u3 = Y2[(size_t)s_3 * 32 + q];
            UP2(u0.x, a0, a1) UP2(u0.y, a2, a3)
            UP2(u1.x, a0, a1) UP2(u1.y, a2, a3)
            UP2(u2.x, a0, a1) UP2(u2.y, a2, a3)
            UP2(u3.x, a0, a1) UP2(u3.y, a2, a3)
        }
        for (; e < cnt; e += 2) {
            const int s_0 = elist[nb_ + e];
            const uint2 u0 = Y2[(size_t)s_0 * 32 + q];
            UP2(u0.x, a0, a1) UP2(u0.y, a2, a3)
        }
        // combine edge-parity halves
        a0 += __shfl_xor(a0, 32);
        a1 += __shfl_xor(a1, 32);
        a2 += __shfl_xor(a2, 32);
        a3 += __shfl_xor(a3, 32);
        // self-loop (post-combine, added once)
        const uint2 us = Y2[(size_t)node * 32 + q];
        UP2(us.x, a0, a1) UP2(us.y, a2, a3)
        const float dv = dinv_s[nid];
        if (half == 0) {
            const float4 r = make_float4(bias.x + a0 * dv, bias.y + a1 * dv,
                                         bias.z + a2 * dv, bias.w + a3 * dv);
            if (q < 16)
                *(float4*)&out[(size_t)node * F_OUT + 4 * q] = r;
            else
                *(float4*)&out[((size_t)N + node) * F_OUT + 4 * (q - 16)] = r;
        }
    }
#undef UP2
}

extern "C" void kernel_launch(void* const* d_in, const int* in_sizes, int n_in,
                              void* d_out, int out_size, void* d_ws, size_t ws_size,
                              hipStream_t stream) {
    const float* x   = (const float*)d_in[0];
    const int*   ei  = (const int*)d_in[1];
    const float* Wmu = (const float*)d_in[2];
    const float* bmu = (const float*)d_in[3];
    const float* Wls = (const float*)d_in[4];
    const float* bls = (const float*)d_in[5];
    float* out = (float*)d_out;

    const int N = in_sizes[0] / F_IN;     // 100000
    const int E = in_sizes[1] / 2;        // 3200000
    const int* row = ei;
    const int* col = ei + E;
    const int NB = (N + 127) >> 7;        // 782 buckets of 128 nodes (<= 1024)
    const int NT = (E + TILE - 1) / TILE; // 782 tiles of 4096 edges (<= 1024)
    const int CAPTOT = NB * CAP;

    // workspace layout (512B aligned):
    char* p = (char*)d_ws;
    auto alloc = [&](size_t bytes) {
        char* r = p;
        p += (bytes + 511) & ~(size_t)511;
        return r;
    };
    int*   cnt   = (int*)  alloc((size_t)NB * NT * 4);
    int*   gbase = (int*)  alloc((size_t)NB * NT * 4);
    int*   totB  = (int*)  alloc((size_t)NB * 4);
    int*   bpk   = (int*)  alloc((size_t)CAPTOT * 4 + 4096);
    int*   deg   = (int*)  alloc((size_t)N * 4);
    float* dinv  = (float*)alloc((size_t)N * 4);
    unsigned int* y = (unsigned int*)alloc((size_t)N * F_IN * 2);

    hist_kernel<<<NT, 256, 0, stream>>>(col, cnt, E, NB, NT);
    scan_kernel<<<NB, 1024, 0, stream>>>(cnt, gbase, totB, NB, NT);
    repack_kernel<<<NT, 256, 0, stream>>>(row, col, gbase, bpk, E, NB, NT, CAPTOT);
    deg_kernel<<<NB, 256, 0, stream>>>(bpk, totB, deg, dinv, N);
    gemm_kernel<<<(N + 63) / 64, 256, 0, stream>>>(x, Wmu, Wls, dinv, y, N);
    bucket_gather<<<NB, 1024, 0, stream>>>(bpk, deg, (const uint2*)y,
                                           bmu, bls, out, N);
}

// Round 10
// 336.598 us; speedup vs baseline: 1.4194x; 1.0999x over previous
//
#include <hip/hip_runtime.h>

#define F_IN 128
#define F_OUT 64
#define TILE 4096
#define CAP 4608   // per-bucket edge capacity: mean 4092, sigma 64 -> +8 sigma

// ---- bf16 helpers (manual, RTN) ----
__device__ inline unsigned short f2bf(float f) {
    unsigned int x = __builtin_bit_cast(unsigned int, f);
    unsigned int r = x + 0x7FFFu + ((x >> 16) & 1u);
    return (unsigned short)(r >> 16);
}

// ---------------- K1: per-tile bucket histogram -> cnt[b][t] ----------------
__global__ __launch_bounds__(256) void hist_kernel(
        const int* __restrict__ col, int* __restrict__ cnt, int E, int NB, int NT) {
    __shared__ int h[1024];
    const int t = threadIdx.x;
    const int tile = blockIdx.x;
    const int base = tile * TILE;
    const int n = min(TILE, E - base);
    for (int i = t; i < 1024; i += 256) h[i] = 0;
    __syncthreads();
    const int4* c4 = (const int4*)(col + base);
    const int n4 = n >> 2;
    for (int i = t; i < n4; i += 256) {
        const int4 c = c4[i];
        atomicAdd(&h[c.x >> 7], 1);
        atomicAdd(&h[c.y >> 7], 1);
        atomicAdd(&h[c.z >> 7], 1);
        atomicAdd(&h[c.w >> 7], 1);
    }
    for (int i = n4 * 4 + t; i < n; i += 256)
        atomicAdd(&h[col[base + i] >> 7], 1);
    __syncthreads();
    for (int b = t; b < NB; b += 256)
        cnt[(size_t)b * NT + tile] = h[b];
}

// ---------------- K2: per-bucket scan over tiles -> gbase[b][t] = b*CAP + prefix ----------------
__global__ __launch_bounds__(1024) void scan_kernel(
        const int* __restrict__ cnt, int* __restrict__ gbase,
        int* __restrict__ totB, int NB, int NT) {
    __shared__ int wsum[16];
    const int b = blockIdx.x;
    const int t = threadIdx.x;
    const int lane = t & 63;
    const int w = t >> 6;
    const int v = (t < NT) ? cnt[(size_t)b * NT + t] : 0;
    int x = v;
#pragma unroll
    for (int off = 1; off < 64; off <<= 1) {
        const int y = __shfl_up(x, off, 64);
        if (lane >= off) x += y;
    }
    if (lane == 63) wsum[w] = x;
    __syncthreads();
    int add = 0;
    for (int i = 0; i < w; i++) add += wsum[i];
    x += add;                               // inclusive scan of v
    if (t < NT) gbase[(size_t)b * NT + t] = b * CAP + (x - v);   // exclusive
    if (t == 1023) totB[b] = x;             // bucket total
}

// ---------------- K3: single-pass repack -> global bucket-major bpk ----------------
__global__ __launch_bounds__(512) void repack_kernel(
        const int* __restrict__ row, const int* __restrict__ col,
        const int* __restrict__ gbase, int* __restrict__ bpk,
        int E, int NB, int NT, int CAPTOT) {
    __shared__ int cur[1024];
    const int t = threadIdx.x;
    const int tile = blockIdx.x;
    const int base = tile * TILE;
    const int n = min(TILE, E - base);
    for (int b = t; b < NB; b += 512)
        cur[b] = gbase[(size_t)b * NT + tile];
    __syncthreads();
    const int4* c4 = (const int4*)(col + base);
    const int4* r4 = (const int4*)(row + base);
    const int n4 = n >> 2;
    for (int i = t; i < n4; i += 512) {
        const int4 c = c4[i];
        const int4 r = r4[i];
        int p0 = atomicAdd(&cur[c.x >> 7], 1);
        int p1 = atomicAdd(&cur[c.y >> 7], 1);
        int p2 = atomicAdd(&cur[c.z >> 7], 1);
        int p3 = atomicAdd(&cur[c.w >> 7], 1);
        if (p0 < CAPTOT) bpk[p0] = r.x | ((c.x & 127) << 17);
        if (p1 < CAPTOT) bpk[p1] = r.y | ((c.y & 127) << 17);
        if (p2 < CAPTOT) bpk[p2] = r.z | ((c.z & 127) << 17);
        if (p3 < CAPTOT) bpk[p3] = r.w | ((c.w & 127) << 17);
    }
    for (int i = n4 * 4 + t; i < n; i += 512) {
        const int c = col[base + i];
        const int pos = atomicAdd(&cur[c >> 7], 1);
        if (pos < CAPTOT)
            bpk[pos] = row[base + i] | ((c & 127) << 17);
    }
}

// ---------------- K4: per-bucket degree -> deg, dinv (coalesced int4 segment read) ----------------
__global__ __launch_bounds__(512) void deg_kernel(
        const int* __restrict__ bpk, const int* __restrict__ totB,
        int* __restrict__ deg, float* __restrict__ dinv, int N) {
    __shared__ int h[128];
    const int b = blockIdx.x;
    const int t = threadIdx.x;
    if (t < 128) h[t] = 0;
    __syncthreads();
    const int tot = min(totB[b], CAP);
    const int4* bp4 = (const int4*)(bpk + b * CAP);
    const int tot4 = tot >> 2;
    for (int i = t; i < tot4; i += 512) {
        const int4 v = bp4[i];
        atomicAdd(&h[v.x >> 17], 1);
        atomicAdd(&h[v.y >> 17], 1);
        atomicAdd(&h[v.z >> 17], 1);
        atomicAdd(&h[v.w >> 17], 1);
    }
    for (int i = tot4 * 4 + t; i < tot; i += 512)
        atomicAdd(&h[bpk[b * CAP + i] >> 17], 1);
    __syncthreads();
    const int node = b * 128 + t;
    if (t < 128 && node < N) {
        deg[node] = h[t];
        dinv[node] = rsqrtf((float)h[t] + 1.0f);   // +1 self-loop
    }
}

// ---------------- gemm: 64 nodes/block; half-wave owns 8 nodes, lane owns col-quad ----------------
__global__ __launch_bounds__(256) void gemm_kernel(
        const float* __restrict__ x, const float* __restrict__ Wmu,
        const float* __restrict__ Wls, const float* __restrict__ dinv,
        unsigned int* __restrict__ y, int N) {
    __shared__ float xs[64 * F_IN];       // 32 KB
    const int tid = threadIdx.x;          // 0..255
    const int base = blockIdx.x * 64;
    const int nn = min(64, N - base);
    {
        const float4* xg = (const float4*)(x + (size_t)base * F_IN);
        float4* xs4 = (float4*)xs;
        const int cnt = nn * (F_IN / 4);
        for (int i = tid; i < cnt; i += 256) xs4[i] = xg[i];
    }
    __syncthreads();
    const int wv = tid >> 6;              // wave 0..3
    const int lane = tid & 63;
    const int half = lane >> 5;           // 0/1
    const int lp = lane & 31;             // 0..31: col-quad owner
    const int nbase = wv * 16 + half * 8; // this half-wave's 8 nodes
    const float* W0 = (lp < 16) ? Wmu : Wls;
    const int coff = (lp < 16) ? (4 * lp) : (4 * (lp - 16));
    float acc[8][4];
#pragma unroll
    for (int n = 0; n < 8; n++)
#pragma unroll
        for (int c = 0; c < 4; c++) acc[n][c] = 0.f;

    for (int k = 0; k < F_IN; k += 4) {
        const float4 w0 = *(const float4*)&W0[(size_t)(k + 0) * F_OUT + coff];
        const float4 w1 = *(const float4*)&W0[(size_t)(k + 1) * F_OUT + coff];
        const float4 w2 = *(const float4*)&W0[(size_t)(k + 2) * F_OUT + coff];
        const float4 w3 = *(const float4*)&W0[(size_t)(k + 3) * F_OUT + coff];
#pragma unroll
        for (int n = 0; n < 8; n++) {
            const float4 xv = *(const float4*)&xs[(nbase + n) * F_IN + k];
            acc[n][0] = fmaf(xv.x, w0.x, acc[n][0]);
            acc[n][1] = fmaf(xv.x, w0.y, acc[n][1]);
            acc[n][2] = fmaf(xv.x, w0.z, acc[n][2]);
            acc[n][3] = fmaf(xv.x, w0.w, acc[n][3]);
            acc[n][0] = fmaf(xv.y, w1.x, acc[n][0]);
            acc[n][1] = fmaf(xv.y, w1.y, acc[n][1]);
            acc[n][2] = fmaf(xv.y, w1.z, acc[n][2]);
            acc[n][3] = fmaf(xv.y, w1.w, acc[n][3]);
            acc[n][0] = fmaf(xv.z, w2.x, acc[n][0]);
            acc[n][1] = fmaf(xv.z, w2.y, acc[n][1]);
            acc[n][2] = fmaf(xv.z, w2.z, acc[n][2]);
            acc[n][3] = fmaf(xv.z, w2.w, acc[n][3]);
            acc[n][0] = fmaf(xv.w, w3.x, acc[n][0]);
            acc[n][1] = fmaf(xv.w, w3.y, acc[n][1]);
            acc[n][2] = fmaf(xv.w, w3.z, acc[n][2]);
            acc[n][3] = fmaf(xv.w, w3.w, acc[n][3]);
        }
    }
    const int ci = (lp < 16) ? (2 * lp) : (32 + 2 * (lp - 16));
#pragma unroll
    for (int n = 0; n < 8; n++) {
        const int node = base + nbase + n;
        if (node < N) {
            const float dv = dinv[node];
            const unsigned u0 = (unsigned)f2bf(acc[n][0] * dv) |
                                ((unsigned)f2bf(acc[n][1] * dv) << 16);
            const unsigned u1 = (unsigned)f2bf(acc[n][2] * dv) |
                                ((unsigned)f2bf(acc[n][3] * dv) << 16);
            *(uint2*)&y[(size_t)node * 64 + ci] = make_uint2(u0, u1);
        }
    }
}

// ---------------- bucket_gather: coalesced segment -> LDS node scatter -> uint4 reg accumulation ----------------
__global__ __launch_bounds__(1024) void bucket_gather(
        const int* __restrict__ bpk, const int* __restrict__ deg,
        const uint4* __restrict__ Y4,
        const float* __restrict__ bmu, const float* __restrict__ bls,
        float* __restrict__ out, int N) {
    __shared__ int elist[CAP];            // 18 KB: node-sorted src ids
    __shared__ int hN[128];
    __shared__ int nodebase[128];
    __shared__ int cursor[128];
    __shared__ float dinv_s[128];
    __shared__ int w0sum;
    const int b = blockIdx.x;
    const int t = threadIdx.x;
    const int lane = t & 63;

    // phase 0: deg row (coalesced) + 128-wide shfl scan -> bases/cursors
    int hv = 0;
    if (t < 128) {
        const int node = b * 128 + t;
        hv = (node < N) ? deg[node] : 0;
        dinv_s[t] = rsqrtf((float)hv + 1.0f);
        hN[t] = hv;
    }
    int x = hv;
#pragma unroll
    for (int off = 1; off < 64; off <<= 1) {
        const int y = __shfl_up(x, off, 64);
        if (lane >= off) x += y;
    }
    if (t == 63) w0sum = x;
    __syncthreads();
    if (t >= 64 && t < 128) x += w0sum;
    if (t < 128) { nodebase[t] = x - hv; cursor[t] = x - hv; }
    __syncthreads();
    const int tot = min(nodebase[127] + hN[127], CAP);

    // phase 1: int4 segment read -> scatter grouped by node
    const int4* bp4 = (const int4*)(bpk + b * CAP);
    const int tot4 = tot >> 2;
    for (int i = t; i < tot4; i += 1024) {
        const int4 v = bp4[i];
        int p0 = atomicAdd(&cursor[v.x >> 17], 1);
        int p1 = atomicAdd(&cursor[v.y >> 17], 1);
        int p2 = atomicAdd(&cursor[v.z >> 17], 1);
        int p3 = atomicAdd(&cursor[v.w >> 17], 1);
        if (p0 < CAP) elist[p0] = v.x & 0x1FFFF;
        if (p1 < CAP) elist[p1] = v.y & 0x1FFFF;
        if (p2 < CAP) elist[p2] = v.z & 0x1FFFF;
        if (p3 < CAP) elist[p3] = v.w & 0x1FFFF;
    }
    for (int i = tot4 * 4 + t; i < tot; i += 1024) {
        const int p = bpk[b * CAP + i];
        const int pos = atomicAdd(&cursor[p >> 17], 1);
        if (pos < CAP) elist[pos] = p & 0x1FFFF;
    }
    __syncthreads();

    // phase 2: wave owns 8 nodes; 16 lanes x uint4 per edge; 4 edges per pass
    const int w = t >> 6;                 // wave 0..15
    const int eg = lane >> 4;             // edge slot 0..3
    const int q = lane & 15;              // uint4 index (feats 8q..8q+7)

#define ACC(u)                                                        \
    do {                                                              \
        A.x += __builtin_bit_cast(float, (u).x << 16);                \
        A.y += __builtin_bit_cast(float, (u).x & 0xFFFF0000u);        \
        A.z += __builtin_bit_cast(float, (u).y << 16);                \
        A.w += __builtin_bit_cast(float, (u).y & 0xFFFF0000u);        \
        B.x += __builtin_bit_cast(float, (u).z << 16);                \
        B.y += __builtin_bit_cast(float, (u).z & 0xFFFF0000u);        \
        B.z += __builtin_bit_cast(float, (u).w << 16);                \
        B.w += __builtin_bit_cast(float, (u).w & 0xFFFF0000u);        \
    } while (0)

    for (int nid = w * 8; nid < w * 8 + 8; nid++) {
        const int node = b * 128 + nid;
        if (node >= N) continue;          // wave-uniform
        const int cnt = hN[nid];
        const int nb_ = nodebase[nid];
        float4 A = make_float4(0.f, 0.f, 0.f, 0.f);
        float4 B = make_float4(0.f, 0.f, 0.f, 0.f);
        int e = 0;
        for (; e + 16 <= cnt; e += 16) {
            const int s0 = elist[nb_ + e + 0 + eg];
            const int s1 = elist[nb_ + e + 4 + eg];
            const int s2 = elist[nb_ + e + 8 + eg];
            const int s3 = elist[nb_ + e + 12 + eg];
            const uint4 u0 = Y4[(size_t)s0 * 16 + q];
            const uint4 u1 = Y4[(size_t)s1 * 16 + q];
            const uint4 u2 = Y4[(size_t)s2 * 16 + q];
            const uint4 u3 = Y4[(size_t)s3 * 16 + q];
            ACC(u0); ACC(u1); ACC(u2); ACC(u3);
        }
        for (; e < cnt; e += 4) {
            if (e + eg < cnt) {
                const int s0 = elist[nb_ + e + eg];
                const uint4 u0 = Y4[(size_t)s0 * 16 + q];
                ACC(u0);
            }
        }
        // combine the 4 edge-slot partials
        A.x += __shfl_xor(A.x, 16); A.y += __shfl_xor(A.y, 16);
        A.z += __shfl_xor(A.z, 16); A.w += __shfl_xor(A.w, 16);
        B.x += __shfl_xor(B.x, 16); B.y += __shfl_xor(B.y, 16);
        B.z += __shfl_xor(B.z, 16); B.w += __shfl_xor(B.w, 16);
        A.x += __shfl_xor(A.x, 32); A.y += __shfl_xor(A.y, 32);
        A.z += __shfl_xor(A.z, 32); A.w += __shfl_xor(A.w, 32);
        B.x += __shfl_xor(B.x, 32); B.y += __shfl_xor(B.y, 32);
        B.z += __shfl_xor(B.z, 32); B.w += __shfl_xor(B.w, 32);
        // self-loop (post-combine, each lane holds the full sum)
        {
            const uint4 u = Y4[(size_t)node * 16 + q];
            ACC(u);
        }
        const float dv = dinv_s[nid];
        if (lane < 16) {
            if (q < 8) {
                const float4 b0 = ((const float4*)bmu)[2 * q];
                const float4 b1 = ((const float4*)bmu)[2 * q + 1];
                float* o = out + (size_t)node * F_OUT + q * 8;
                *(float4*)o = make_float4(b0.x + A.x * dv, b0.y + A.y * dv,
                                          b0.z + A.z * dv, b0.w + A.w * dv);
                *(float4*)(o + 4) = make_float4(b1.x + B.x * dv, b1.y + B.y * dv,
                                                b1.z + B.z * dv, b1.w + B.w * dv);
            } else {
                const float4 b0 = ((const float4*)bls)[2 * (q - 8)];
                const float4 b1 = ((const float4*)bls)[2 * (q - 8) + 1];
                float* o = out + ((size_t)N + node) * F_OUT + (q - 8) * 8;
                *(float4*)o = make_float4(b0.x + A.x * dv, b0.y + A.y * dv,
                                          b0.z + A.z * dv, b0.w + A.w * dv);
                *(float4*)(o + 4) = make_float4(b1.x + B.x * dv, b1.y + B.y * dv,
                                                b1.z + B.z * dv, b1.w + B.w * dv);
            }
        }
    }
#undef ACC
}

extern "C" void kernel_launch(void* const* d_in, const int* in_sizes, int n_in,
                              void* d_out, int out_size, void* d_ws, size_t ws_size,
                              hipStream_t stream) {
    const float* x   = (const float*)d_in[0];
    const int*   ei  = (const int*)d_in[1];
    const float* Wmu = (const float*)d_in[2];
    const float* bmu = (const float*)d_in[3];
    const float* Wls = (const float*)d_in[4];
    const float* bls = (const float*)d_in[5];
    float* out = (float*)d_out;

    const int N = in_sizes[0] / F_IN;     // 100000
    const int E = in_sizes[1] / 2;        // 3200000
    const int* row = ei;
    const int* col = ei + E;
    const int NB = (N + 127) >> 7;        // 782 buckets of 128 nodes (<= 1024)
    const int NT = (E + TILE - 1) / TILE; // 782 tiles of 4096 edges (<= 1024)
    const int CAPTOT = NB * CAP;

    // workspace layout (512B aligned):
    char* p = (char*)d_ws;
    auto alloc = [&](size_t bytes) {
        char* r = p;
        p += (bytes + 511) & ~(size_t)511;
        return r;
    };
    int*   cnt   = (int*)  alloc((size_t)NB * NT * 4);
    int*   gbase = (int*)  alloc((size_t)NB * NT * 4);
    int*   totB  = (int*)  alloc((size_t)NB * 4);
    int*   bpk   = (int*)  alloc((size_t)CAPTOT * 4 + 4096);
    int*   deg   = (int*)  alloc((size_t)N * 4);
    float* dinv  = (float*)alloc((size_t)N * 4);
    unsigned int* y = (unsigned int*)alloc((size_t)N * F_IN * 2);

    hist_kernel<<<NT, 256, 0, stream>>>(col, cnt, E, NB, NT);
    scan_kernel<<<NB, 1024, 0, stream>>>(cnt, gbase, totB, NB, NT);
    repack_kernel<<<NT, 512, 0, stream>>>(row, col, gbase, bpk, E, NB, NT, CAPTOT);
    deg_kernel<<<NB, 512, 0, stream>>>(bpk, totB, deg, dinv, N);
    gemm_kernel<<<(N + 63) / 64, 256, 0, stream>>>(x, Wmu, Wls, dinv, y, N);
    bucket_gather<<<NB, 1024, 0, stream>>>(bpk, deg, (const uint4*)y,
                                           bmu, bls, out, N);
}